// Round 6
// baseline (360.796 us; speedup 1.0000x reference)
//
#include <hip/hip_runtime.h>
#include <hip/hip_bf16.h>

// GAT encoder, 2 layers. B=32, N=512, D=64, H=8, DK=8.
// Layer: xp = x@W -> s,t per head -> masked softmax over sources i per target j
//        -> out[j,h,:] = sum_i alpha * xp[i,h,:]  -> +bias, relu.
//
// R2 design notes:
//  - Softmax shift m[j,h] = lrelu(smax[b,h] + t[j,h]) is a FIXED upper bound
//    (leaky_relu monotone), so partial (acc,l) sums over disjoint i-ranges are
//    directly addable -> split-i x4 (2048 blocks, 8/CU) + f32 atomicAdd combine.
//  - T14: prefetch next i-chunk into regs during compute, commit after barrier.
//  - smax fused into proj epilogue: block max + atomicMax on monotone uint keys.

namespace {

constexpr int NB = 32;      // batch
constexpr int NN = 512;     // nodes
constexpr int SPLITS = 4;   // i-splits in aggr
constexpr float SLOPE = 0.2f;

__device__ __forceinline__ float lrelu(float x) { return x > 0.f ? x : SLOPE * x; }

// monotone f32 <-> u32 key map (key order == float order); key 0 = minimum
__device__ __forceinline__ unsigned enc_key(float f) {
    union { float f; unsigned u; } v; v.f = f;
    return (v.u & 0x80000000u) ? ~v.u : (v.u | 0x80000000u);
}
__device__ __forceinline__ float dec_key(unsigned k) {
    union { float f; unsigned u; } v;
    v.u = (k & 0x80000000u) ? (k ^ 0x80000000u) : ~k;
    return v.f;
}

// ---------------- zero scratch (acc, l, keys contiguous) --------------------
__global__ __launch_bounds__(256) void gat_zero(float* __restrict__ p, int n) {
    const int i = blockIdx.x * 256 + threadIdx.x;
    if (i < n) p[i] = 0.0f;
}

// ---------------- Kernel A: xp = x@W ; s,t ; fused per-(b,h) s-max ----------
// grid: (B*N/32) blocks, 256 threads. Thread (r=tid>>3, h=tid&7).
__global__ __launch_bounds__(256) void gat_proj(
    const float* __restrict__ x,     // [B*N, 64]
    const float* __restrict__ W,     // [64, 64]
    const float* __restrict__ asrc,  // [8, 8]
    const float* __restrict__ adst,  // [8, 8]
    float* __restrict__ xp,          // [B*N, 64]
    float* __restrict__ s,           // [B*N, 8]
    float* __restrict__ t,           // [B*N, 8]
    unsigned* __restrict__ keys)     // [B, 8] monotone-encoded smax
{
    __shared__ float Wl[64 * 64];
    __shared__ float xs[32 * 65];    // stride 65: kills 8-way bank conflict
    __shared__ float red[256];
    const int tid = threadIdx.x;
    const int row0 = blockIdx.x * 32;

    for (int q = tid; q < 4096; q += 256) Wl[q] = W[q];
    for (int q = tid; q < 2048; q += 256) xs[(q >> 6) * 65 + (q & 63)] = x[row0 * 64 + q];
    __syncthreads();

    const int r = tid >> 3, h = tid & 7;
    float acc[8] = {};
    const float* xr = &xs[r * 65];
    #pragma unroll 8
    for (int k = 0; k < 64; ++k) {
        const float xv = xr[k];
        #pragma unroll
        for (int d = 0; d < 8; ++d)
            acc[d] = fmaf(xv, Wl[k * 64 + h * 8 + d], acc[d]);
    }
    const int row = row0 + r;
    float4* xpo = reinterpret_cast<float4*>(&xp[row * 64 + h * 8]);
    xpo[0] = make_float4(acc[0], acc[1], acc[2], acc[3]);
    xpo[1] = make_float4(acc[4], acc[5], acc[6], acc[7]);

    float sv = 0.f, tv = 0.f;
    #pragma unroll
    for (int d = 0; d < 8; ++d) {
        sv = fmaf(acc[d], asrc[h * 8 + d], sv);
        tv = fmaf(acc[d], adst[h * 8 + d], tv);
    }
    s[row * 8 + h] = sv;
    t[row * 8 + h] = tv;

    // block-level max over the 32 rows for each h, then one atomic per h
    red[tid] = sv;
    __syncthreads();
    #pragma unroll
    for (int off = 128; off >= 8; off >>= 1) {
        if (tid < off) red[tid] = fmaxf(red[tid], red[tid + off]);
        __syncthreads();
    }
    if (tid < 8) {
        const int b = row0 >> 9;               // 512 rows per batch
        atomicMax(&keys[b * 8 + tid], enc_key(red[tid]));
    }
}

// ---------------- Kernel B: masked softmax over i + aggregation -------------
// grid: (N/32 j-tiles, B, SPLITS); 256 threads; thread (jj=tid>>3, h=tid&7)
// owns target j = j0+jj, head h; accumulates over NN/SPLITS sources.
__global__ __launch_bounds__(256) void gat_aggr(
    const float* __restrict__ xp,    // [B*N, 64]
    const float* __restrict__ s,     // [B*N, 8]
    const float* __restrict__ t,     // [B*N, 8]
    const unsigned* __restrict__ keys, // [B, 8]
    const int*   __restrict__ adj,   // [B, N, N]  adj[b,i,j]
    float* __restrict__ acc_g,       // [B*N, 64] partial-sum target (atomic)
    float* __restrict__ l_g)         // [B*N, 8]  partial-denominator (atomic)
{
    __shared__ float xpl[32 * 64];   // xp chunk: 32 sources x 64
    __shared__ float sl[32 * 8];     // s  chunk: 32 sources x 8 heads
    __shared__ float ml[32 * 32];    // mask chunk: 32 sources x 32 targets

    const int tid = threadIdx.x;
    const int b = blockIdx.y;
    const int j0 = blockIdx.x * 32;
    const int ibase = blockIdx.z * (NN / SPLITS);
    const int jj = tid >> 3, h = tid & 7;
    const int j = j0 + jj;

    const float tv = t[(b * NN + j) * 8 + h];
    const float m = lrelu(dec_key(keys[b * 8 + h]) + tv);  // upper bound on all e

    float acc[8] = {};
    float l = 0.f;

    // T14 prefetch registers
    float4 pa, pb; float ps; int pm[4];

    auto issue = [&](int i0) {
        const float4* src = reinterpret_cast<const float4*>(&xp[(b * NN + i0) * 64]);
        pa = src[tid];
        pb = src[tid + 256];
        ps = s[(b * NN + i0) * 8 + tid];
        #pragma unroll
        for (int rep = 0; rep < 4; ++rep) {
            const int q = rep * 256 + tid;
            pm[rep] = adj[(b * NN + i0 + (q >> 5)) * NN + j0 + (q & 31)];
        }
    };

    issue(ibase);

    for (int c = 0; c < NN / SPLITS / 32; ++c) {
        const int i0 = ibase + c * 32;
        __syncthreads();                      // previous compute done; LDS free
        // commit prefetched chunk to LDS
        {
            float4* dst = reinterpret_cast<float4*>(xpl);
            dst[tid] = pa;
            dst[tid + 256] = pb;
            sl[tid] = ps;
            #pragma unroll
            for (int rep = 0; rep < 4; ++rep) {
                const int q = rep * 256 + tid;
                const int gi = i0 + (q >> 5);
                ml[q] = (pm[rep] != 0 || gi == j0 + (q & 31)) ? 1.0f : 0.0f;
            }
        }
        // issue next chunk's loads (latency hides under compute below)
        if (c + 1 < NN / SPLITS / 32) issue(i0 + 32);
        __syncthreads();                      // LDS visible

        #pragma unroll
        for (int ii = 0; ii < 32; ++ii) {
            const float e = lrelu(sl[ii * 8 + h] + tv);
            const float p = ml[ii * 32 + jj] * __expf(e - m);
            l += p;
            const float4* xr = reinterpret_cast<const float4*>(&xpl[ii * 64 + h * 8]);
            const float4 xa = xr[0], xb = xr[1];
            acc[0] = fmaf(p, xa.x, acc[0]);
            acc[1] = fmaf(p, xa.y, acc[1]);
            acc[2] = fmaf(p, xa.z, acc[2]);
            acc[3] = fmaf(p, xa.w, acc[3]);
            acc[4] = fmaf(p, xb.x, acc[4]);
            acc[5] = fmaf(p, xb.y, acc[5]);
            acc[6] = fmaf(p, xb.z, acc[6]);
            acc[7] = fmaf(p, xb.w, acc[7]);
        }
    }

    float* ap = &acc_g[(b * NN + j) * 64 + h * 8];
    #pragma unroll
    for (int d = 0; d < 8; ++d) unsafeAtomicAdd(&ap[d], acc[d]);
    unsafeAtomicAdd(&l_g[(b * NN + j) * 8 + h], l);
}

// ---------------- Kernel C: out = relu(acc/l + bias) ------------------------
// grid: B*N*64/256 blocks.
__global__ __launch_bounds__(256) void gat_fin(
    const float* __restrict__ acc_g, // [B*N, 64]
    const float* __restrict__ l_g,   // [B*N, 8]
    const float* __restrict__ bias,  // [64]
    float* __restrict__ outp)        // [B*N, 64]
{
    const int idx = blockIdx.x * 256 + threadIdx.x;
    const float a = acc_g[idx];
    const float lv = l_g[idx >> 3];
    const float bv = bias[idx & 63];
    outp[idx] = fmaxf(fmaf(a, __builtin_amdgcn_rcpf(lv), bv), 0.0f);
}

} // namespace

extern "C" void kernel_launch(void* const* d_in, const int* in_sizes, int n_in,
                              void* d_out, int out_size, void* d_ws, size_t ws_size,
                              hipStream_t stream) {
    const float* n_in0  = (const float*)d_in[0];   // [B,N,64]
    const int*   adj    = (const int*)d_in[1];     // [B,N,N]
    const float* W1     = (const float*)d_in[2];
    const float* asrc1  = (const float*)d_in[3];
    const float* adst1  = (const float*)d_in[4];
    const float* b1     = (const float*)d_in[5];
    const float* W2     = (const float*)d_in[6];
    const float* asrc2  = (const float*)d_in[7];
    const float* adst2  = (const float*)d_in[8];
    const float* b2     = (const float*)d_in[9];

    float* ws = (float*)d_ws;
    float* xp   = ws;                    // 1048576 floats
    float* s    = xp + 1048576;          // 131072
    float* t    = s + 131072;            // 131072
    float* x2   = t + 131072;            // 1048576
    float* acc  = x2 + 1048576;          // 1048576   [acc][l][keys] contiguous
    float* l    = acc + 1048576;         // 131072
    unsigned* keys = (unsigned*)(l + 131072);  // 256 u32 (pad to 512)
    const int zero_n = 1048576 + 131072 + 512;

    const dim3 blk(256);
    const dim3 gZero((zero_n + 255) / 256);
    const dim3 gProj(NB * NN / 32);
    const dim3 gAggr(NN / 32, NB, SPLITS);
    const dim3 gFin(NB * NN * 64 / 256);

    // Layer 1
    gat_zero<<<gZero, blk, 0, stream>>>(acc, zero_n);
    gat_proj<<<gProj, blk, 0, stream>>>(n_in0, W1, asrc1, adst1, xp, s, t, keys);
    gat_aggr<<<gAggr, blk, 0, stream>>>(xp, s, t, keys, adj, acc, l);
    gat_fin<<<gFin, blk, 0, stream>>>(acc, l, b1, x2);
    // Layer 2
    gat_zero<<<gZero, blk, 0, stream>>>(acc, zero_n);
    gat_proj<<<gProj, blk, 0, stream>>>(x2, W2, asrc2, adst2, xp, s, t, keys);
    gat_aggr<<<gAggr, blk, 0, stream>>>(xp, s, t, keys, adj, acc, l);
    gat_fin<<<gFin, blk, 0, stream>>>(acc, l, b2, (float*)d_out);
}

// Round 7
// 193.758 us; speedup vs baseline: 1.8621x; 1.8621x over previous
//
#include <hip/hip_runtime.h>
#include <hip/hip_bf16.h>

// GAT encoder, 2 layers. B=32, N=512, D=64, H=8, DK=8.
// Layer: xp = x@W -> s,t per head -> masked softmax over sources i per target j
//        -> out[j,h,:] = sum_i alpha * xp[i,h,:]  -> +bias, relu.
//
// R7 design notes:
//  - Softmax shift m[j,h] = lrelu(smax[b,h] + t[j,h]) is a FIXED upper bound
//    (leaky_relu monotone) -> single pass over i, exp arg <= 0.
//  - R6 lesson: global f32 atomicAdd combine = 133 MB HBM write-through RMW
//    traffic (cross-XCD coherence) -> NEVER dense-combine via atomics.
//  - This round: split over j (block = (b, 8 targets), all 512 sources),
//    grid 64x32=2048 blocks; 256 thr = (iq 4 x jj 8 x h 8); iq-partials
//    reduced in LDS; final out written in-block. No fin/zero/atomic combine.
//  - T14: prefetch next i-chunk into regs during compute, commit after barrier.

namespace {

constexpr int NB = 32;      // batch
constexpr int NN = 512;     // nodes
constexpr float SLOPE = 0.2f;

__device__ __forceinline__ float lrelu(float x) { return x > 0.f ? x : SLOPE * x; }

// monotone f32 <-> u32 key map (key order == float order); key 0 = minimum
__device__ __forceinline__ unsigned enc_key(float f) {
    union { float f; unsigned u; } v; v.f = f;
    return (v.u & 0x80000000u) ? ~v.u : (v.u | 0x80000000u);
}
__device__ __forceinline__ float dec_key(unsigned k) {
    union { float f; unsigned u; } v;
    v.u = (k & 0x80000000u) ? (k ^ 0x80000000u) : ~k;
    return v.f;
}

// ---------------- zero the 256 smax keys ------------------------------------
__global__ __launch_bounds__(256) void gat_zkeys(unsigned* __restrict__ keys) {
    keys[threadIdx.x] = 0u;
}

// ---------------- Kernel A: xp = x@W ; s,t ; fused per-(b,h) s-max ----------
// grid: (B*N/32) blocks, 256 threads. Thread (r=tid>>3, h=tid&7).
__global__ __launch_bounds__(256) void gat_proj(
    const float* __restrict__ x,     // [B*N, 64]
    const float* __restrict__ W,     // [64, 64]
    const float* __restrict__ asrc,  // [8, 8]
    const float* __restrict__ adst,  // [8, 8]
    float* __restrict__ xp,          // [B*N, 64]
    float* __restrict__ s,           // [B*N, 8]
    float* __restrict__ t,           // [B*N, 8]
    unsigned* __restrict__ keys)     // [B, 8] monotone-encoded smax
{
    __shared__ float Wl[64 * 64];
    __shared__ float xs[32 * 65];    // stride 65: kills 8-way bank conflict
    __shared__ float red[256];
    const int tid = threadIdx.x;
    const int row0 = blockIdx.x * 32;

    for (int q = tid; q < 4096; q += 256) Wl[q] = W[q];
    for (int q = tid; q < 2048; q += 256) xs[(q >> 6) * 65 + (q & 63)] = x[row0 * 64 + q];
    __syncthreads();

    const int r = tid >> 3, h = tid & 7;
    float acc[8] = {};
    const float* xr = &xs[r * 65];
    #pragma unroll 8
    for (int k = 0; k < 64; ++k) {
        const float xv = xr[k];
        #pragma unroll
        for (int d = 0; d < 8; ++d)
            acc[d] = fmaf(xv, Wl[k * 64 + h * 8 + d], acc[d]);
    }
    const int row = row0 + r;
    float4* xpo = reinterpret_cast<float4*>(&xp[row * 64 + h * 8]);
    xpo[0] = make_float4(acc[0], acc[1], acc[2], acc[3]);
    xpo[1] = make_float4(acc[4], acc[5], acc[6], acc[7]);

    float sv = 0.f, tv = 0.f;
    #pragma unroll
    for (int d = 0; d < 8; ++d) {
        sv = fmaf(acc[d], asrc[h * 8 + d], sv);
        tv = fmaf(acc[d], adst[h * 8 + d], tv);
    }
    s[row * 8 + h] = sv;
    t[row * 8 + h] = tv;

    // block-level max over the 32 rows for each h, then one atomic per h
    red[tid] = sv;
    __syncthreads();
    #pragma unroll
    for (int off = 128; off >= 8; off >>= 1) {
        if (tid < off) red[tid] = fmaxf(red[tid], red[tid + off]);
        __syncthreads();
    }
    if (tid < 8) {
        const int b = row0 >> 9;               // 512 rows per batch
        atomicMax(&keys[b * 8 + tid], enc_key(red[tid]));
    }
}

// ---------------- Kernel B: masked softmax over i + aggregation -------------
// grid: (N/8 j-tiles, B); 256 threads = (iq=tid>>6, jj=(tid>>3)&7, h=tid&7).
// Block owns targets j0..j0+7, ALL 512 sources; thread accumulates its
// i-quarter (strided chunks), then 4-way LDS reduction over iq; 64 threads
// write relu(acc/l + bias) directly. No global combine.
__global__ __launch_bounds__(256) void gat_aggr(
    const float* __restrict__ xp,    // [B*N, 64]
    const float* __restrict__ s,     // [B*N, 8]
    const float* __restrict__ t,     // [B*N, 8]
    const unsigned* __restrict__ keys, // [B, 8]
    const int*   __restrict__ adj,   // [B, N, N]  adj[b,i,j]
    const float* __restrict__ bias,  // [64]
    float* __restrict__ outp)        // [B*N, 64]
{
    __shared__ float xpl[32 * 64];   // xp chunk: 32 sources x 64       (8 KB)
    __shared__ float sl[32 * 8];     // s  chunk: 32 sources x 8 heads  (1 KB)
    __shared__ float ml[32 * 8];     // mask chunk: 32 sources x 8 tgts (1 KB)
    __shared__ float red[4 * 64 * 9];// iq-partials, stride 9 (2-way ok) (9 KB)

    const int tid = threadIdx.x;
    const int b = blockIdx.y;
    const int j0 = blockIdx.x * 8;
    const int iq = tid >> 6;         // which i-quarter of each chunk
    const int jj = (tid >> 3) & 7;
    const int h  = tid & 7;
    const int j  = j0 + jj;

    const float tv = t[(b * NN + j) * 8 + h];
    const float m = lrelu(dec_key(keys[b * 8 + h]) + tv);  // >= all e for this (j,h)

    float acc[8] = {};
    float l = 0.f;

    // T14 prefetch registers
    float4 pa, pb; float ps; int pm;

    auto issue = [&](int i0) {
        const float4* src = reinterpret_cast<const float4*>(&xp[(b * NN + i0) * 64]);
        pa = src[tid];
        pb = src[tid + 256];
        ps = s[(b * NN + i0) * 8 + tid];
        pm = adj[(b * NN + i0 + (tid >> 3)) * NN + j0 + (tid & 7)];
    };

    issue(0);

    for (int c = 0; c < NN / 32; ++c) {
        const int i0 = c * 32;
        __syncthreads();                      // previous compute done; LDS free
        // commit prefetched chunk to LDS
        reinterpret_cast<float4*>(xpl)[tid] = pa;
        reinterpret_cast<float4*>(xpl)[tid + 256] = pb;
        sl[tid] = ps;
        ml[tid] = (pm != 0 || (i0 + (tid >> 3)) == (j0 + (tid & 7))) ? 1.0f : 0.0f;
        // issue next chunk's loads (latency hides under compute below)
        if (c + 1 < NN / 32) issue(i0 + 32);
        __syncthreads();                      // LDS visible

        #pragma unroll
        for (int u = 0; u < 8; ++u) {
            const int ii = iq * 8 + u;
            const float e = lrelu(sl[ii * 8 + h] + tv);
            const float p = ml[ii * 8 + jj] * __expf(e - m);
            l += p;
            const float4* xr = reinterpret_cast<const float4*>(&xpl[ii * 64 + h * 8]);
            const float4 xa = xr[0], xb = xr[1];
            acc[0] = fmaf(p, xa.x, acc[0]);
            acc[1] = fmaf(p, xa.y, acc[1]);
            acc[2] = fmaf(p, xa.z, acc[2]);
            acc[3] = fmaf(p, xa.w, acc[3]);
            acc[4] = fmaf(p, xb.x, acc[4]);
            acc[5] = fmaf(p, xb.y, acc[5]);
            acc[6] = fmaf(p, xb.z, acc[6]);
            acc[7] = fmaf(p, xb.w, acc[7]);
        }
    }

    // 4-way reduction over iq via LDS (stride 9 -> 2-way bank alias = free)
    float* rb = &red[(iq * 64 + jj * 8 + h) * 9];
    #pragma unroll
    for (int d = 0; d < 8; ++d) rb[d] = acc[d];
    rb[8] = l;
    __syncthreads();

    if (tid < 64) {                   // tid = jj*8 + h
        float o[9];
        #pragma unroll
        for (int d = 0; d < 9; ++d) o[d] = red[tid * 9 + d];
        #pragma unroll
        for (int q = 1; q < 4; ++q)
            #pragma unroll
            for (int d = 0; d < 9; ++d) o[d] += red[(q * 64 + tid) * 9 + d];

        const int hh = tid & 7;
        const float rec = 1.0f / o[8];
        float r[8];
        #pragma unroll
        for (int d = 0; d < 8; ++d)
            r[d] = fmaxf(fmaf(o[d], rec, bias[hh * 8 + d]), 0.0f);

        const int row = b * NN + j0 + (tid >> 3);
        float4* po = reinterpret_cast<float4*>(&outp[row * 64 + hh * 8]);
        po[0] = make_float4(r[0], r[1], r[2], r[3]);
        po[1] = make_float4(r[4], r[5], r[6], r[7]);
    }
}

} // namespace

extern "C" void kernel_launch(void* const* d_in, const int* in_sizes, int n_in,
                              void* d_out, int out_size, void* d_ws, size_t ws_size,
                              hipStream_t stream) {
    const float* n_in0  = (const float*)d_in[0];   // [B,N,64]
    const int*   adj    = (const int*)d_in[1];     // [B,N,N]
    const float* W1     = (const float*)d_in[2];
    const float* asrc1  = (const float*)d_in[3];
    const float* adst1  = (const float*)d_in[4];
    const float* b1     = (const float*)d_in[5];
    const float* W2     = (const float*)d_in[6];
    const float* asrc2  = (const float*)d_in[7];
    const float* adst2  = (const float*)d_in[8];
    const float* b2     = (const float*)d_in[9];

    float* ws = (float*)d_ws;
    float* xp   = ws;                    // 1048576 floats
    float* s    = xp + 1048576;          // 131072
    float* t    = s + 131072;            // 131072
    float* x2   = t + 131072;            // 1048576
    unsigned* keys = (unsigned*)(x2 + 1048576); // 256 u32

    const dim3 blk(256);
    const dim3 gProj(NB * NN / 32);
    const dim3 gAggr(NN / 8, NB);

    // Layer 1
    gat_zkeys<<<1, blk, 0, stream>>>(keys);
    gat_proj<<<gProj, blk, 0, stream>>>(n_in0, W1, asrc1, adst1, xp, s, t, keys);
    gat_aggr<<<gAggr, blk, 0, stream>>>(xp, s, t, keys, adj, b1, x2);
    // Layer 2
    gat_zkeys<<<1, blk, 0, stream>>>(keys);
    gat_proj<<<gProj, blk, 0, stream>>>(x2, W2, asrc2, adst2, xp, s, t, keys);
    gat_aggr<<<gAggr, blk, 0, stream>>>(xp, s, t, keys, adj, b2, (float*)d_out);
}

// Round 9
// 183.932 us; speedup vs baseline: 1.9616x; 1.0534x over previous
//
#include <hip/hip_runtime.h>
#include <hip/hip_bf16.h>

// GAT encoder, 2 layers. B=32, N=512, D=64, H=8, DK=8.
// Layer: xp = x@W -> s,t per head -> masked softmax over sources i per target j
//        -> out[j,h,:] = sum_i alpha * xp[i,h,:]  -> +bias, relu.
//
// Design ledger:
//  - Softmax shift m[j,h] = lrelu(smax[b,h] + t[j,h]) is a FIXED upper bound
//    (leaky_relu monotone) -> single pass over i, exp arg <= 0. (R2, verified)
//  - R6 lesson: global f32 atomicAdd dense combine = 133 MB HBM RMW traffic.
//  - R7: j-split blocks, in-block LDS combine: 52 us aggr, but adj 32B slices
//    over-fetched 2x (FETCH 84.5 MB) and proj path ~90 us unaccounted.
//  - R8 (this): j-tile 16 + 512 thr (adj 64B lines, 32 waves/CU);
//    pmax[B][16][8] dense store instead of zkeys+atomicMax (-2 dispatches).

namespace {

constexpr int NB = 32;      // batch
constexpr int NN = 512;     // nodes
constexpr float SLOPE = 0.2f;

__device__ __forceinline__ float lrelu(float x) { return x > 0.f ? x : SLOPE * x; }

// ---------------- Kernel A: xp = x@W ; s,t ; per-block s-max -> pmax --------
// grid: (B*N/32) blocks, 256 threads. Thread (r=tid>>3, h=tid&7).
__global__ __launch_bounds__(256) void gat_proj(
    const float* __restrict__ x,     // [B*N, 64]
    const float* __restrict__ W,     // [64, 64]
    const float* __restrict__ asrc,  // [8, 8]
    const float* __restrict__ adst,  // [8, 8]
    float* __restrict__ xp,          // [B*N, 64]
    float* __restrict__ s,           // [B*N, 8]
    float* __restrict__ t,           // [B*N, 8]
    float* __restrict__ pmax)        // [B, 16, 8] per-block s-max (dense)
{
    __shared__ float Wl[64 * 64];
    __shared__ float xs[32 * 65];    // stride 65: kills 8-way bank conflict
    __shared__ float red[256];
    const int tid = threadIdx.x;
    const int row0 = blockIdx.x * 32;

    for (int q = tid; q < 4096; q += 256) Wl[q] = W[q];
    for (int q = tid; q < 2048; q += 256) xs[(q >> 6) * 65 + (q & 63)] = x[row0 * 64 + q];
    __syncthreads();

    const int r = tid >> 3, h = tid & 7;
    float acc[8] = {};
    const float* xr = &xs[r * 65];
    #pragma unroll 8
    for (int k = 0; k < 64; ++k) {
        const float xv = xr[k];
        #pragma unroll
        for (int d = 0; d < 8; ++d)
            acc[d] = fmaf(xv, Wl[k * 64 + h * 8 + d], acc[d]);
    }
    const int row = row0 + r;
    float4* xpo = reinterpret_cast<float4*>(&xp[row * 64 + h * 8]);
    xpo[0] = make_float4(acc[0], acc[1], acc[2], acc[3]);
    xpo[1] = make_float4(acc[4], acc[5], acc[6], acc[7]);

    float sv = 0.f, tv = 0.f;
    #pragma unroll
    for (int d = 0; d < 8; ++d) {
        sv = fmaf(acc[d], asrc[h * 8 + d], sv);
        tv = fmaf(acc[d], adst[h * 8 + d], tv);
    }
    s[row * 8 + h] = sv;
    t[row * 8 + h] = tv;

    // block-level max over the 32 rows for each h; dense store (no atomics)
    red[tid] = sv;
    __syncthreads();
    #pragma unroll
    for (int off = 128; off >= 8; off >>= 1) {
        if (tid < off) red[tid] = fmaxf(red[tid], red[tid + off]);
        __syncthreads();
    }
    if (tid < 8) {
        // blockIdx.x = b*16 + q  (32 rows/block, 512 rows/batch)
        pmax[blockIdx.x * 8 + tid] = red[tid];
    }
}

// ---------------- Kernel B: masked softmax over i + aggregation -------------
// grid: (N/16 j-tiles, B); 512 threads; mapping: iq = tid>>7 (4 i-quarters),
// jj = (tid>>3)&15, h = tid&7.
// Block owns targets j0..j0+15, ALL 512 sources; iq-partials reduced in LDS;
// 128 threads write relu(acc/l + bias) directly. No global combine.
__global__ __launch_bounds__(512) void gat_aggr(
    const float* __restrict__ xp,    // [B*N, 64]
    const float* __restrict__ s,     // [B*N, 8]
    const float* __restrict__ t,     // [B*N, 8]
    const float* __restrict__ pmax,  // [B, 16, 8]
    const int*   __restrict__ adj,   // [B, N, N]  adj[b,i,j]
    const float* __restrict__ bias,  // [64]
    float* __restrict__ outp)        // [B*N, 64]
{
    __shared__ float xpl[32 * 64];    // xp chunk: 32 sources x 64       (8 KB)
    __shared__ float sl[32 * 8];      // s  chunk: 32 sources x 8 heads  (1 KB)
    __shared__ float ml[32 * 16];     // mask chunk: 32 src x 16 tgts    (2 KB)
    __shared__ float red[4 * 128 * 9];// iq-partials, stride 9           (18 KB)

    const int tid = threadIdx.x;
    const int b = blockIdx.y;
    const int j0 = blockIdx.x * 16;
    const int iq = tid >> 7;         // i-quarter of each 32-chunk
    const int jj = (tid >> 3) & 15;
    const int h  = tid & 7;
    const int j  = j0 + jj;

    // smax[b,h] = max over the 16 proj-block maxima
    float sm = pmax[b * 128 + h];
    #pragma unroll
    for (int q = 1; q < 16; ++q) sm = fmaxf(sm, pmax[b * 128 + q * 8 + h]);

    const float tv = t[(b * NN + j) * 8 + h];
    const float m = lrelu(sm + tv);   // >= all e for this (j,h)

    float acc[8] = {};
    float l = 0.f;

    // T14 prefetch registers (1 float4 + 1 float + 1 int per thread)
    float4 pa; float ps; int pm;

    auto issue = [&](int i0) {
        pa = reinterpret_cast<const float4*>(&xp[(b * NN + i0) * 64])[tid];
        if (tid < 256) ps = s[(b * NN + i0) * 8 + tid];
        pm = adj[(b * NN + i0 + (tid >> 4)) * NN + j0 + (tid & 15)];
    };

    issue(0);

    for (int c = 0; c < NN / 32; ++c) {
        const int i0 = c * 32;
        __syncthreads();                      // previous compute done; LDS free
        // commit prefetched chunk to LDS
        reinterpret_cast<float4*>(xpl)[tid] = pa;
        if (tid < 256) sl[tid] = ps;
        ml[tid] = (pm != 0 || (i0 + (tid >> 4)) == (j0 + (tid & 15))) ? 1.0f : 0.0f;
        // issue next chunk's loads (latency hides under compute below)
        if (c + 1 < NN / 32) issue(i0 + 32);
        __syncthreads();                      // LDS visible

        #pragma unroll
        for (int u = 0; u < 8; ++u) {
            const int ii = iq * 8 + u;
            const float e = lrelu(sl[ii * 8 + h] + tv);
            const float p = ml[ii * 16 + jj] * __expf(e - m);
            l += p;
            const float4* xr = reinterpret_cast<const float4*>(&xpl[ii * 64 + h * 8]);
            const float4 xa = xr[0], xb = xr[1];
            acc[0] = fmaf(p, xa.x, acc[0]);
            acc[1] = fmaf(p, xa.y, acc[1]);
            acc[2] = fmaf(p, xa.z, acc[2]);
            acc[3] = fmaf(p, xa.w, acc[3]);
            acc[4] = fmaf(p, xb.x, acc[4]);
            acc[5] = fmaf(p, xb.y, acc[5]);
            acc[6] = fmaf(p, xb.z, acc[6]);
            acc[7] = fmaf(p, xb.w, acc[7]);
        }
    }

    // 4-way reduction over iq via LDS (stride 9: lanes spread over banks)
    float* rb = &red[(iq * 128 + jj * 8 + h) * 9];
    #pragma unroll
    for (int d = 0; d < 8; ++d) rb[d] = acc[d];
    rb[8] = l;
    __syncthreads();

    if (tid < 128) {                  // tid = jj*8 + h
        float o[9];
        #pragma unroll
        for (int d = 0; d < 9; ++d) o[d] = red[tid * 9 + d];
        #pragma unroll
        for (int q = 1; q < 4; ++q)
            #pragma unroll
            for (int d = 0; d < 9; ++d) o[d] += red[(q * 128 + tid) * 9 + d];

        const int hh = tid & 7;
        const float rec = 1.0f / o[8];
        float r[8];
        #pragma unroll
        for (int d = 0; d < 8; ++d)
            r[d] = fmaxf(fmaf(o[d], rec, bias[hh * 8 + d]), 0.0f);

        const int row = b * NN + j0 + (tid >> 3);
        float4* po = reinterpret_cast<float4*>(&outp[row * 64 + hh * 8]);
        po[0] = make_float4(r[0], r[1], r[2], r[3]);
        po[1] = make_float4(r[4], r[5], r[6], r[7]);
    }
}

} // namespace

extern "C" void kernel_launch(void* const* d_in, const int* in_sizes, int n_in,
                              void* d_out, int out_size, void* d_ws, size_t ws_size,
                              hipStream_t stream) {
    const float* n_in0  = (const float*)d_in[0];   // [B,N,64]
    const int*   adj    = (const int*)d_in[1];     // [B,N,N]
    const float* W1     = (const float*)d_in[2];
    const float* asrc1  = (const float*)d_in[3];
    const float* adst1  = (const float*)d_in[4];
    const float* b1     = (const float*)d_in[5];
    const float* W2     = (const float*)d_in[6];
    const float* asrc2  = (const float*)d_in[7];
    const float* adst2  = (const float*)d_in[8];
    const float* b2     = (const float*)d_in[9];

    float* ws = (float*)d_ws;
    float* xp   = ws;                    // 1048576 floats
    float* s    = xp + 1048576;          // 131072
    float* t    = s + 131072;            // 131072
    float* x2   = t + 131072;            // 1048576
    float* pmax = x2 + 1048576;          // 4096 (dense-written every call)

    const dim3 gProj(NB * NN / 32);
    const dim3 gAggr(NN / 16, NB);

    // Layer 1
    gat_proj<<<gProj, 256, 0, stream>>>(n_in0, W1, asrc1, adst1, xp, s, t, pmax);
    gat_aggr<<<gAggr, 512, 0, stream>>>(xp, s, t, pmax, adj, b1, x2);
    // Layer 2
    gat_proj<<<gProj, 256, 0, stream>>>(x2, W2, asrc2, adst2, xp, s, t, pmax);
    gat_aggr<<<gAggr, 512, 0, stream>>>(xp, s, t, pmax, adj, b2, (float*)d_out);
}